// Round 6
// baseline (309.235 us; speedup 1.0000x reference)
//
#include <hip/hip_runtime.h>
#include <hip/hip_fp16.h>

#define BG 64
#define NN 2048
#define MM 2048
#define CC 64
#define HH 128
#define NNZE 32768
#define TH 384  // 3*H

typedef float f4v __attribute__((ext_vector_type(4)));  // nt-builtin rejects HIP float4
typedef __attribute__((ext_vector_type(8))) short bf16x8;
typedef __attribute__((ext_vector_type(4))) float f32x4;
typedef unsigned short u16;

// RNE f32 -> bf16 (no NaN in data paths here)
static __device__ __forceinline__ u16 bf16rne(float f) {
    uint u = __float_as_uint(f);
    uint r = u + 0x7FFFu + ((u >> 16) & 1u);
    return (u16)(r >> 16);
}
static __device__ __forceinline__ float bf16tof(u16 h) {
    return __uint_as_float(((uint)h) << 16);
}

// ---------------- merged prep: count + scan + bin + x->fp16 + W split, 1 block/graph ----------------
// R16: prep_count/prep_scan/prep_bin merged. Evidence: "total - spmm" is a stable ~198us across
// ALL rounds while each non-spmm kernel is individually <59.5us (invisible below top-5). The old
// 3-kernel prep ran 1024-thr blocks at 1 block/CU -> every block's serial chain (cold loads ->
// LDS atomics -> 8 barriers -> scattered stores) fully latency-exposed, plus rows loaded twice
// from HBM and ~12 MB of count/offset tables round-tripped through global between kernels.
// Merged per-graph: offsets stay LDS-resident, no cnt_blk merge (scan logic SIMPLIFIES from the
// verified prep_scan), flag = (slot == cnt-1), 2 launch gaps removed. Row-internal edge order
// becomes atomic-order (was per-quarter deterministic): fp sum-order noise ~1e-6 only.
__global__ __launch_bounds__(1024) void prep_all_kernel(
    const int* __restrict__ d_rows, const int* __restrict__ d_cols,
    const float* __restrict__ d_vals, const int* __restrict__ d_index,
    const float* __restrict__ x,
    const float* __restrict__ Wq, const float* __restrict__ Wk,
    const float* __restrict__ Wv,
    uint* __restrict__ xh, u16* __restrict__ WhT, u16* __restrict__ WlT,
    int* __restrict__ cnt_clu_g, int* __restrict__ off_clu_g,
    int* __restrict__ row_edge_off_g, int2* __restrict__ epack) {
    __shared__ int cnt_row_s[MM];   // 8 KB: per-row edge counts (live through bin)
    __shared__ int off_row_s[MM];   // 8 KB: per-row base offset (cluster-major)
    __shared__ int fill_s[MM];      // 8 KB: bin fill counters
    __shared__ int rlist_s[MM];     // 8 KB: rows in cluster-major order
    __shared__ int cnt_clu_s[CC], off_clu_s[CC], fill_clu_s[CC];
    __shared__ int wsum[16];
    int g = blockIdx.x, t = threadIdx.x;
    int lane = t & 63, w = t >> 6;

    cnt_row_s[t] = 0;
    cnt_row_s[t + 1024] = 0;
    fill_s[t] = 0;
    fill_s[t + 1024] = 0;
    if (t < CC) {
        cnt_clu_s[t] = 0;
        fill_clu_s[t] = 0;
    }
    int idx0 = d_index[(g << 11) + t];
    int idx1 = d_index[(g << 11) + t + 1024];
    __syncthreads();

    // ---- count: 32 edges/thread, int4-coalesced; cluster counts ----
    const int4* rows4 = (const int4*)(d_rows + ((size_t)g << 15));
#pragma unroll
    for (int it = 0; it < 8; it++) {
        int4 r = rows4[it * 1024 + t];
        atomicAdd(&cnt_row_s[r.x], 1);
        atomicAdd(&cnt_row_s[r.y], 1);
        atomicAdd(&cnt_row_s[r.z], 1);
        atomicAdd(&cnt_row_s[r.w], 1);
    }
    atomicAdd(&cnt_clu_s[idx0], 1);
    atomicAdd(&cnt_clu_s[idx1], 1);
    __syncthreads();

    // ---- cluster scan (wave 0) ----
    if (t < CC) {
        int v = cnt_clu_s[t];
        int incl = v;
#pragma unroll
        for (int d = 1; d < 64; d <<= 1) {
            int u = __shfl_up(incl, d);
            if (t >= d) incl += u;
        }
        off_clu_s[t] = incl - v;
        cnt_clu_g[(g << 6) + t] = v;
        off_clu_g[(g << 6) + t] = incl - v;
    }
    __syncthreads();

    // ---- rlist: rows in cluster-major order ----
    {
        int s0 = atomicAdd(&fill_clu_s[idx0], 1);
        rlist_s[off_clu_s[idx0] + s0] = t;
        int s1 = atomicAdd(&fill_clu_s[idx1], 1);
        rlist_s[off_clu_s[idx1] + s1] = t + 1024;
    }
    __syncthreads();

    // ---- cluster-major scan of row totals (thread t owns j=2t, 2t+1) ----
    int r0 = rlist_s[2 * t], r1 = rlist_s[2 * t + 1];
    int c0 = cnt_row_s[r0], c1 = cnt_row_s[r1];
    int s = c0 + c1;
    int incl = s;
#pragma unroll
    for (int d = 1; d < 64; d <<= 1) {
        int u = __shfl_up(incl, d);
        if (lane >= d) incl += u;
    }
    if (lane == 63) wsum[w] = incl;
    __syncthreads();
    if (t < 16) {
        int v = wsum[t], iv = v;
#pragma unroll
        for (int d = 1; d < 16; d <<= 1) {
            int u = __shfl_up(iv, d);
            if (t >= d) iv += u;
        }
        wsum[t] = iv - v;  // exclusive
    }
    __syncthreads();
    {
        int base = wsum[w] + incl - s;
        int* reo = row_edge_off_g + g * (MM + 1);
        reo[2 * t] = base;
        reo[2 * t + 1] = base + c0;
        off_row_s[r0] = base;
        off_row_s[r1] = base + c0;
        if (t == 0) reo[MM] = NNZE;
    }
    __syncthreads();

    // ---- bin: reload edges; slot via fill atomic; flag when slot == cnt-1 ----
    const int4* cols4 = (const int4*)(d_cols + ((size_t)g << 15));
    const f4v* vals4 = (const f4v*)(d_vals + ((size_t)g << 15));
    int2* epg = epack + ((size_t)g << 15);
#pragma unroll
    for (int it = 0; it < 8; it++) {
        int4 r = rows4[it * 1024 + t];
        int4 c = cols4[it * 1024 + t];
        f4v v = vals4[it * 1024 + t];
        {
            int sl = atomicAdd(&fill_s[r.x], 1);
            int flag = (sl == cnt_row_s[r.x] - 1) ? (int)0x80000000 : 0;
            epg[off_row_s[r.x] + sl] = make_int2(c.x | flag, __float_as_int(v.x));
        }
        {
            int sl = atomicAdd(&fill_s[r.y], 1);
            int flag = (sl == cnt_row_s[r.y] - 1) ? (int)0x80000000 : 0;
            epg[off_row_s[r.y] + sl] = make_int2(c.y | flag, __float_as_int(v.y));
        }
        {
            int sl = atomicAdd(&fill_s[r.z], 1);
            int flag = (sl == cnt_row_s[r.z] - 1) ? (int)0x80000000 : 0;
            epg[off_row_s[r.z] + sl] = make_int2(c.z | flag, __float_as_int(v.z));
        }
        {
            int sl = atomicAdd(&fill_s[r.w], 1);
            int flag = (sl == cnt_row_s[r.w] - 1) ? (int)0x80000000 : 0;
            epg[off_row_s[r.w] + sl] = make_int2(c.w | flag, __float_as_int(v.w));
        }
    }

    // ---- x (fp32) -> xh (fp16 RNE, 2 feats/uint): this graph's 1 MB ----
    // (no barrier needed: consumers are later kernels)
    {
        const f4v* x4 = (const f4v*)(x + ((size_t)g << 18));
        uint4* xh4 = (uint4*)(xh + ((size_t)g << 17));
#pragma unroll 4
        for (int it = 0; it < 32; it++) {
            int gi = it * 1024 + t;  // group-of-8-floats within graph
            f4v a = __builtin_nontemporal_load(&x4[2 * gi]);
            f4v b = __builtin_nontemporal_load(&x4[2 * gi + 1]);
            __half2 h0 = __float22half2_rn(make_float2(a.x, a.y));
            __half2 h1 = __float22half2_rn(make_float2(a.z, a.w));
            __half2 h2 = __float22half2_rn(make_float2(b.x, b.y));
            __half2 h3 = __float22half2_rn(make_float2(b.z, b.w));
            uint4 o;
            o.x = *(uint*)&h0;
            o.y = *(uint*)&h1;
            o.z = *(uint*)&h2;
            o.w = *(uint*)&h3;
            xh4[gi] = o;
        }
    }
    // ---- W split+transpose: 147456 elems / 64 blocks = 2304 per block ----
    for (int i = t; i < 2304; i += 1024) {
        int id = g * 2304 + i;
        int wsel = id / 49152;
        int r = id - wsel * 49152;  // r = k*128 + n
        const float* Ws = (wsel == 0) ? Wq : (wsel == 1) ? Wk : Wv;
        float v = Ws[r];
        int k = r >> 7, n = r & 127;
        u16 hi = bf16rne(v);
        u16 lo = bf16rne(v - bf16tof(hi));
        WhT[wsel * 49152 + n * 384 + k] = hi;
        WlT[wsel * 49152 + n * 384 + k] = lo;
    }
}

// ---------------- fused SpMM + mean/max/sum pooling, one wave64 per cluster, fp16 x ----------------
// R0 inner loop (60.6us; best of 4 structures tried -- R11/R12/R14 all regressed: per-CU
// scattered-line rate ~4.4cy/line is the HW ceiling and R0 already sits on it).
// Epilogue writes xdec as split-bf16 (hi + lo = fp32-accurate pair) for the MFMA qkv.
__global__ __launch_bounds__(64) void spmm_pool_kernel(const uint* __restrict__ xh,
                                                       const int* __restrict__ cnt_clu,
                                                       const int* __restrict__ off_clu,
                                                       const int* __restrict__ row_edge_off,
                                                       const int2* __restrict__ epack,
                                                       u16* __restrict__ xdh,
                                                       u16* __restrict__ xdl) {
    // XCD-aware swizzle: bid&7 -> XCD, graphs [8q, 8q+7] on XCD q
    int bid = blockIdx.x;
    int l = bid >> 3;
    int g = ((bid & 7) << 3) + (l >> 6);
    int c = l & 63;
    int h = threadIdx.x;  // 0..63
    int gc = (g << 6) + c;
    int rcnt = cnt_clu[gc];
    int j0 = off_clu[gc];
    const int* reo = row_edge_off + g * (MM + 1) + j0;
    int ebase = reo[0];
    int etot = reo[rcnt] - ebase;
    const long long* ep = (const long long*)(epack + ((size_t)g << 15)) + ebase;
    const uint* xg = xh + ((size_t)g << 17);  // g*N*(H/2) uints
    float2 coef = make_float2(0.f, 0.f), sum = make_float2(0.f, 0.f);
    float2 mx = make_float2(-__builtin_inff(), -__builtin_inff());
    int e = 0;
    for (; e + 16 <= etot; e += 16) {
        long long q[16];
#pragma unroll
        for (int k = 0; k < 16; k++) q[k] = __builtin_nontemporal_load(&ep[e + k]);
        uint xv[16];
#pragma unroll
        for (int k = 0; k < 16; k++)
            xv[k] = xg[(((uint)(int)q[k] & 0x7FFFFFFFu) << 6) + h];
#pragma unroll
        for (int k = 0; k < 16; k++) {
            float v = __int_as_float((int)(q[k] >> 32));
            float2 f = __half22float2(*(__half2*)&xv[k]);
            coef.x = fmaf(v, f.x, coef.x);
            coef.y = fmaf(v, f.y, coef.y);
            if ((int)q[k] < 0) {  // wave-uniform (all lanes see same edge)
                sum.x += coef.x; sum.y += coef.y;
                mx.x = fmaxf(mx.x, coef.x); mx.y = fmaxf(mx.y, coef.y);
                coef.x = 0.f; coef.y = 0.f;
            }
        }
    }
    for (; e < etot; e++) {
        long long q = ep[e];
        uint xv = xg[(((uint)(int)q & 0x7FFFFFFFu) << 6) + h];
        float v = __int_as_float((int)(q >> 32));
        float2 f = __half22float2(*(__half2*)&xv);
        coef.x = fmaf(v, f.x, coef.x);
        coef.y = fmaf(v, f.y, coef.y);
        if ((int)q < 0) {
            sum.x += coef.x; sum.y += coef.y;
            mx.x = fmaxf(mx.x, coef.x); mx.y = fmaxf(mx.y, coef.y);
            coef.x = 0.f; coef.y = 0.f;
        }
    }
    // rows with zero edges contribute coef==0 to the max
    int az = 0;
    for (int j = h; j < rcnt; j += 64) az |= (reo[j + 1] == reo[j]);
    if (__ballot(az) != 0ULL) {
        mx.x = fmaxf(mx.x, 0.f);
        mx.y = fmaxf(mx.y, 0.f);
    }
    float inv = 1.f / (float)(rcnt > 0 ? rcnt : 1);
    // split-bf16 epilogue: lane h owns feature pair (2h, 2h+1) of each of mean|max|sum
    uint* oh = (uint*)xdh + (size_t)gc * 192 + h;
    uint* ol = (uint*)xdl + (size_t)gc * 192 + h;
    float me0 = sum.x * inv, me1 = sum.y * inv;
    u16 a0 = bf16rne(me0), a1 = bf16rne(me1);
    oh[0] = (uint)a0 | ((uint)a1 << 16);
    ol[0] = (uint)bf16rne(me0 - bf16tof(a0)) | ((uint)bf16rne(me1 - bf16tof(a1)) << 16);
    u16 b0 = bf16rne(mx.x), b1 = bf16rne(mx.y);
    oh[64] = (uint)b0 | ((uint)b1 << 16);
    ol[64] = (uint)bf16rne(mx.x - bf16tof(b0)) | ((uint)bf16rne(mx.y - bf16tof(b1)) << 16);
    u16 c0 = bf16rne(sum.x), c1 = bf16rne(sum.y);
    oh[128] = (uint)c0 | ((uint)c1 << 16);
    ol[128] = (uint)bf16rne(sum.x - bf16tof(c0)) | ((uint)bf16rne(sum.y - bf16tof(c1)) << 16);
}

// ---------------- QKV projection via split-bf16 triple-MFMA (verified R15, absmax unchanged) ----------------
__global__ __launch_bounds__(256) void qkv_kernel(const u16* __restrict__ xdh,
                                                  const u16* __restrict__ xdl,
                                                  const u16* __restrict__ WhT,
                                                  const u16* __restrict__ WlT,
                                                  float* __restrict__ QKV) {
    __shared__ u16 Ah[64][40], Al[64][40], Bh[64][40], Bl[64][40];
    int bx = blockIdx.x, by = blockIdx.y;
    int t = threadIdx.x;
    int w = by >> 1;
    int cb = (by & 1) << 6;     // col base within this W
    int r0 = bx << 6;
    const u16* wh = WhT + w * 49152;
    const u16* wl = WlT + w * 49152;
    int lane = t & 63, wv = t >> 6;
    int wm = wv >> 1, wn = wv & 1;          // wave -> 32x32 quadrant
    int srow = t >> 2, sks = (t & 3) << 3;  // staging: row, k-chunk (8 elems)
    int fr = lane & 15, fk = (lane >> 4) << 3;  // fragment row/col + k base
    f32x4 acc[2][2];
#pragma unroll
    for (int i = 0; i < 2; i++)
#pragma unroll
        for (int j = 0; j < 2; j++)
#pragma unroll
            for (int r = 0; r < 4; r++) acc[i][j][r] = 0.f;
    for (int ks = 0; ks < 12; ks++) {
        int k0 = ks << 5;
        bf16x8 sa_h = *(const bf16x8*)&xdh[(size_t)(r0 + srow) * 384 + k0 + sks];
        bf16x8 sa_l = *(const bf16x8*)&xdl[(size_t)(r0 + srow) * 384 + k0 + sks];
        bf16x8 sb_h = *(const bf16x8*)&wh[(size_t)(cb + srow) * 384 + k0 + sks];
        bf16x8 sb_l = *(const bf16x8*)&wl[(size_t)(cb + srow) * 384 + k0 + sks];
        if (ks) __syncthreads();  // previous iteration's fragment reads must finish
        *(bf16x8*)&Ah[srow][sks] = sa_h;
        *(bf16x8*)&Al[srow][sks] = sa_l;
        *(bf16x8*)&Bh[srow][sks] = sb_h;
        *(bf16x8*)&Bl[srow][sks] = sb_l;
        __syncthreads();
        bf16x8 fa_h[2], fa_l[2], fb_h[2], fb_l[2];
#pragma unroll
        for (int mi = 0; mi < 2; mi++) {
            int ar = (wm << 5) + (mi << 4) + fr;
            fa_h[mi] = *(const bf16x8*)&Ah[ar][fk];
            fa_l[mi] = *(const bf16x8*)&Al[ar][fk];
        }
#pragma unroll
        for (int ni = 0; ni < 2; ni++) {
            int br = (wn << 5) + (ni << 4) + fr;
            fb_h[ni] = *(const bf16x8*)&Bh[br][fk];
            fb_l[ni] = *(const bf16x8*)&Bl[br][fk];
        }
#pragma unroll
        for (int mi = 0; mi < 2; mi++)
#pragma unroll
            for (int ni = 0; ni < 2; ni++) {
                acc[mi][ni] = __builtin_amdgcn_mfma_f32_16x16x32_bf16(
                    fa_h[mi], fb_h[ni], acc[mi][ni], 0, 0, 0);
                acc[mi][ni] = __builtin_amdgcn_mfma_f32_16x16x32_bf16(
                    fa_h[mi], fb_l[ni], acc[mi][ni], 0, 0, 0);
                acc[mi][ni] = __builtin_amdgcn_mfma_f32_16x16x32_bf16(
                    fa_l[mi], fb_h[ni], acc[mi][ni], 0, 0, 0);
            }
    }
#pragma unroll
    for (int mi = 0; mi < 2; mi++)
#pragma unroll
        for (int ni = 0; ni < 2; ni++)
#pragma unroll
            for (int r = 0; r < 4; r++) {
                int row = r0 + (wm << 5) + (mi << 4) + ((lane >> 4) << 2) + r;
                int col = (by << 6) + (wn << 5) + (ni << 4) + (lane & 15);
                QKV[(size_t)row * TH + col] = acc[mi][ni][r];
            }
}

// ---------------- per-graph 64x64 attention ----------------
__global__ __launch_bounds__(256) void attn_kernel(const float* __restrict__ QKV,
                                                   float* __restrict__ out) {
    __shared__ float Qs[16][132];
    __shared__ float sc[16][68];
    int g = blockIdx.x;
    int q0 = blockIdx.y * 16;
    int t = threadIdx.x;
    const float* base = QKV + (size_t)(g * CC) * TH;
    for (int u = t; u < 512; u += 256) {
        int i = u >> 5, cc = u & 31;
        *(float4*)&Qs[i][cc * 4] = *(const float4*)&base[(size_t)(q0 + i) * TH + cc * 4];
    }
    __syncthreads();
    {  // scores: thread (iq, j) computes rows iq, iq+4, iq+8, iq+12 vs col j
        int j = t & 63, iq = t >> 6;
        float a0 = 0, a1 = 0, a2 = 0, a3 = 0;
        const float* Krow = base + (size_t)j * TH + HH;
#pragma unroll 4
        for (int cc = 0; cc < 32; cc++) {
            float4 kv = *(const float4*)&Krow[cc * 4];
            float4 q0v = *(float4*)&Qs[iq][cc * 4];
            float4 q1v = *(float4*)&Qs[4 + iq][cc * 4];
            float4 q2v = *(float4*)&Qs[8 + iq][cc * 4];
            float4 q3v = *(float4*)&Qs[12 + iq][cc * 4];
            a0 += kv.x * q0v.x + kv.y * q0v.y + kv.z * q0v.z + kv.w * q0v.w;
            a1 += kv.x * q1v.x + kv.y * q1v.y + kv.z * q1v.z + kv.w * q1v.w;
            a2 += kv.x * q2v.x + kv.y * q2v.y + kv.z * q2v.z + kv.w * q2v.w;
            a3 += kv.x * q3v.x + kv.y * q3v.y + kv.z * q3v.z + kv.w * q3v.w;
        }
        const float scale = 0.08838834764831845f;  // 1/sqrt(128)
        sc[iq][j] = a0 * scale;
        sc[4 + iq][j] = a1 * scale;
        sc[8 + iq][j] = a2 * scale;
        sc[12 + iq][j] = a3 * scale;
    }
    __syncthreads();
    {  // softmax: 16 threads per row, 4 cols each
        int i = t >> 4, l = t & 15;
        float4 sv = *(float4*)&sc[i][l * 4];
        float m = fmaxf(fmaxf(sv.x, sv.y), fmaxf(sv.z, sv.w));
#pragma unroll
        for (int d = 1; d < 16; d <<= 1) m = fmaxf(m, __shfl_xor(m, d));
        float4 p;
        p.x = __expf(sv.x - m);
        p.y = __expf(sv.y - m);
        p.z = __expf(sv.z - m);
        p.w = __expf(sv.w - m);
        float s = p.x + p.y + p.z + p.w;
#pragma unroll
        for (int d = 1; d < 16; d <<= 1) s += __shfl_xor(s, d);
        float inv = 1.0f / s;
        p.x *= inv; p.y *= inv; p.z *= inv; p.w *= inv;
        *(float4*)&sc[i][l * 4] = p;
    }
    __syncthreads();
    {  // PV: thread (i, hq) computes out[i][hq*8 .. +8)
        int i = t >> 4, hq = t & 15;
        const float* Vbase = base + 2 * HH;
        float acc[8] = {};
        for (int j = 0; j < 64; j++) {
            float d = sc[i][j];
            float4 v0 = *(const float4*)&Vbase[(size_t)j * TH + hq * 8];
            float4 v1 = *(const float4*)&Vbase[(size_t)j * TH + hq * 8 + 4];
            acc[0] = fmaf(d, v0.x, acc[0]);
            acc[1] = fmaf(d, v0.y, acc[1]);
            acc[2] = fmaf(d, v0.z, acc[2]);
            acc[3] = fmaf(d, v0.w, acc[3]);
            acc[4] = fmaf(d, v1.x, acc[4]);
            acc[5] = fmaf(d, v1.y, acc[5]);
            acc[6] = fmaf(d, v1.z, acc[6]);
            acc[7] = fmaf(d, v1.w, acc[7]);
        }
        float* op = out + (size_t)g * (CC * HH) + (size_t)(q0 + i) * HH + hq * 8;
        *(float4*)&op[0] = make_float4(acc[0], acc[1], acc[2], acc[3]);
        *(float4*)&op[4] = make_float4(acc[4], acc[5], acc[6], acc[7]);
    }
}

extern "C" void kernel_launch(void* const* d_in, const int* in_sizes, int n_in,
                              void* d_out, int out_size, void* d_ws, size_t ws_size,
                              hipStream_t stream) {
    const float* x = (const float*)d_in[0];
    // d_in[1] = batch (unused: nodes sorted, equal graph sizes), d_in[2] = batch_size (compile-time 64)
    const int* d_rows = (const int*)d_in[3];
    const int* d_cols = (const int*)d_in[4];
    const float* d_vals = (const float*)d_in[5];
    const int* d_index = (const int*)d_in[6];
    const float* Wq = (const float*)d_in[7];
    const float* Wk = (const float*)d_in[8];
    const float* Wv = (const float*)d_in[9];
    float* out = (float*)d_out;

    char* ws = (char*)d_ws;
    size_t o = 0;
    uint* xh = (uint*)(ws + o); o += (size_t)BG * NN * (HH / 2) * 4;  // 32 MB fp16 x
    int2* epack = (int2*)(ws + o); o += (size_t)BG * NNZE * 8;        // 16 MB
    int* row_edge_off = (int*)(ws + o); o += (size_t)BG * (MM + 1) * 4;
    int* cnt_clu = (int*)(ws + o); o += (size_t)BG * CC * 4;
    int* off_clu = (int*)(ws + o); o += (size_t)BG * CC * 4;
    u16* xdh = (u16*)(ws + o); o += (size_t)BG * CC * TH * 2;   // 3 MB split-bf16 hi
    u16* xdl = (u16*)(ws + o); o += (size_t)BG * CC * TH * 2;   // 3 MB split-bf16 lo
    u16* WhT = (u16*)(ws + o); o += (size_t)3 * HH * TH * 2;    // 288 KB W^T hi
    u16* WlT = (u16*)(ws + o); o += (size_t)3 * HH * TH * 2;    // 288 KB W^T lo
    float* QKV = (float*)(ws + o); o += (size_t)BG * CC * TH * 4;

    prep_all_kernel<<<BG, 1024, 0, stream>>>(d_rows, d_cols, d_vals, d_index, x,
                                             Wq, Wk, Wv, xh, WhT, WlT,
                                             cnt_clu, off_clu, row_edge_off, epack);
    spmm_pool_kernel<<<BG * CC, 64, 0, stream>>>(xh, cnt_clu, off_clu, row_edge_off,
                                                 epack, xdh, xdl);
    qkv_kernel<<<dim3(64, 6), 256, 0, stream>>>(xdh, xdl, WhT, WlT, QKV);
    attn_kernel<<<dim3(BG, 4), 256, 0, stream>>>(QKV, out);
}

// Round 8
// 255.168 us; speedup vs baseline: 1.2119x; 1.2119x over previous
//
#include <hip/hip_runtime.h>
#include <hip/hip_fp16.h>

#define BG 64
#define NN 2048
#define MM 2048
#define CC 64
#define HH 128
#define NNZE 32768
#define TH 384  // 3*H

typedef float f4v __attribute__((ext_vector_type(4)));  // nt-builtin rejects HIP float4
typedef __attribute__((ext_vector_type(8))) short bf16x8;
typedef __attribute__((ext_vector_type(4))) float f32x4;
typedef unsigned short u16;

// RNE f32 -> bf16 (no NaN in data paths here)
static __device__ __forceinline__ u16 bf16rne(float f) {
    uint u = __float_as_uint(f);
    uint r = u + 0x7FFFu + ((u >> 16) & 1u);
    return (u16)(r >> 16);
}
static __device__ __forceinline__ float bf16tof(u16 h) {
    return __uint_as_float(((uint)h) << 16);
}

// ---------------- prep phase A + fused x->fp16 + fused W bf16-split ----------------
// R18: cluster-count atomics removed (scanbin derives cluster tables deterministically).
__global__ __launch_bounds__(1024) void prep_count_kernel(const int* __restrict__ d_rows,
                                                          const float* __restrict__ x,
                                                          const float* __restrict__ Wq,
                                                          const float* __restrict__ Wk,
                                                          const float* __restrict__ Wv,
                                                          int* __restrict__ cnt_blk,
                                                          uint* __restrict__ xh,
                                                          u16* __restrict__ WhT,
                                                          u16* __restrict__ WlT) {
    __shared__ int cnt_row_s[MM];
    int gb = blockIdx.x;  // g*4 + b
    int g = gb >> 2, b = gb & 3;
    int t = threadIdx.x;
    cnt_row_s[t] = 0;
    cnt_row_s[t + 1024] = 0;
    __syncthreads();
    const int* rows_g = d_rows + ((size_t)g << 15) + (b << 13);
#pragma unroll
    for (int it = 0; it < 8; it++) atomicAdd(&cnt_row_s[rows_g[it * 1024 + t]], 1);

    // fused x (fp32) -> xh (fp16 RNE, 2 feats/uint)
    {
        const f4v* x4 = (const f4v*)x;
        uint4* xh4 = (uint4*)xh;
#pragma unroll
        for (int it = 0; it < 8; it++) {
            int tidg = (gb << 13) + it * 1024 + t;  // 8-float group index
            f4v a = __builtin_nontemporal_load(&x4[2 * tidg]);
            f4v bb = __builtin_nontemporal_load(&x4[2 * tidg + 1]);
            __half2 h0 = __float22half2_rn(make_float2(a.x, a.y));
            __half2 h1 = __float22half2_rn(make_float2(a.z, a.w));
            __half2 h2 = __float22half2_rn(make_float2(bb.x, bb.y));
            __half2 h3 = __float22half2_rn(make_float2(bb.z, bb.w));
            uint4 o;
            o.x = *(uint*)&h0;
            o.y = *(uint*)&h1;
            o.z = *(uint*)&h2;
            o.w = *(uint*)&h3;
            xh4[tidg] = o;
        }
    }
    // fused W split+transpose: 3*384*128 = 147456 elems over blocks 0..143
    if (gb < 144) {
        int id = (gb << 10) + t;
        int w = id / 49152;
        int r = id - w * 49152;          // r = k*128 + n
        const float* Ws = (w == 0) ? Wq : (w == 1) ? Wk : Wv;
        float v = Ws[r];
        int k = r >> 7, n = r & 127;
        u16 hi = bf16rne(v);
        u16 lo = bf16rne(v - bf16tof(hi));
        WhT[w * 49152 + n * 384 + k] = hi;
        WlT[w * 49152 + n * 384 + k] = lo;
    }
    __syncthreads();
    int* cb = cnt_blk + (size_t)gb * MM;
    cb[t] = cnt_row_s[t];
    cb[t + 1024] = cnt_row_s[t + 1024];
}

// ---------------- prep B+C merged: DETERMINISTIC per-graph scan + per-quarter bin ----------------
// R17 crashed: rlist built with atomicAdd gave each of a graph's 4 blocks a DIFFERENT row order
// -> inconsistent off_row -> overlapping/unwritten epack slots -> spmm gathered a garbage col ->
// device fault. R18 fix: no rlist/atomics. Within-cluster row order = ascending row index.
// Each wave owns 128 consecutive rows; a 64-cluster loop does a packed segmented prefix
// (edges | 1<<17: low 17 bits edge-prefix, high bits row-rank) via shfl_up -- bit-exact in every
// block. Cross-wave/cluster prefixes are sums of per-wave totals (commutative -> deterministic).
// Packing safe: edges <= 32768 < 2^17, ranks <= 2048. All 4 quarter-blocks of graph g share
// bid%8 -> same XCD so epack partial-line writes combine in one L2.
__global__ __launch_bounds__(1024) void prep_scanbin_kernel(
    const int* __restrict__ d_rows, const int* __restrict__ d_cols,
    const float* __restrict__ d_vals, const int* __restrict__ d_index,
    const int* __restrict__ cnt_blk,
    int* __restrict__ cnt_clu_g, int* __restrict__ off_clu_g,
    int* __restrict__ row_edge_off_g, int2* __restrict__ epack) {
    __shared__ int base_s[MM];    // pre_b; later += off_row = my-block write base
    __shared__ int end_s[MM];     // rowtot; later off_row + rowtot = row end
    __shared__ int fill_s[MM];    // bin fill counters
    __shared__ int wcnt[16][CC];  // packed per-wave per-cluster totals
    __shared__ int off_pack[CC];  // packed exclusive cluster prefix (edges | rows<<17)
    int bid = blockIdx.x;
    int g = ((bid & 7) << 3) | ((bid >> 3) & 7);  // 4 quarters of g share bid%8 -> same XCD
    int b = bid >> 6;
    int t = threadIdx.x;
    int lane = t & 63, w = t >> 6;

    fill_s[t] = 0;
    fill_s[t + 1024] = 0;
    const int* cb = cnt_blk + ((size_t)g << 2) * MM;
    for (int r = t; r < MM; r += 1024) {
        int c0 = cb[r], c1 = cb[MM + r], c2 = cb[2 * MM + r], c3 = cb[3 * MM + r];
        base_s[r] = (b > 0 ? c0 : 0) + (b > 1 ? c1 : 0) + (b > 2 ? c2 : 0);
        end_s[r] = c0 + c1 + c2 + c3;
    }
    int r0 = (w << 7) + 2 * lane;  // this thread's two rows (globally ascending order)
    int r1 = r0 + 1;
    int idx0 = d_index[(g << 11) + r0];
    int idx1 = d_index[(g << 11) + r1];
    __syncthreads();

    int tot0 = end_s[r0], tot1 = end_s[r1];
    // deterministic within-wave segmented prefix over 64 clusters
    int lp0 = 0, lp1 = 0;  // packed local prefix for r0, r1
    for (int c = 0; c < CC; c++) {
        int v0 = (idx0 == c) ? (tot0 | (1 << 17)) : 0;
        int v1 = (idx1 == c) ? (tot1 | (1 << 17)) : 0;
        int pv = v0 + v1;
        int incl = pv;
#pragma unroll
        for (int d = 1; d < 64; d <<= 1) {
            int u = __shfl_up(incl, d);
            if (lane >= d) incl += u;
        }
        int excl = incl - pv;
        if (idx0 == c) lp0 = excl;
        if (idx1 == c) lp1 = excl + v0;
        if (lane == 63) wcnt[w][c] = incl;
    }
    __syncthreads();
    // packed exclusive scan over clusters of per-cluster totals (wave 0)
    if (t < CC) {
        int tot = 0;
#pragma unroll
        for (int ww = 0; ww < 16; ww++) tot += wcnt[ww][t];
        int incl = tot;
#pragma unroll
        for (int d = 1; d < 64; d <<= 1) {
            int u = __shfl_up(incl, d);
            if (t >= d) incl += u;
        }
        off_pack[t] = incl - tot;
        if (b == 0) {
            cnt_clu_g[(g << 6) + t] = tot >> 17;
            off_clu_g[(g << 6) + t] = (incl - tot) >> 17;
        }
    }
    __syncthreads();
    // absolute per-row offsets; reo (b==0 only); update base_s/end_s (rows uniquely owned)
    {
        int wb0 = off_pack[idx0], wb1 = off_pack[idx1];
        for (int ww = 0; ww < w; ww++) {
            wb0 += wcnt[ww][idx0];
            wb1 += wcnt[ww][idx1];
        }
        int p0 = wb0 + lp0, p1 = wb1 + lp1;
        int off0 = p0 & 0x1FFFF, rk0 = p0 >> 17;
        int off1 = p1 & 0x1FFFF, rk1 = p1 >> 17;
        if (b == 0) {
            int* reo = row_edge_off_g + g * (MM + 1);
            reo[rk0] = off0;
            reo[rk1] = off1;
            if (t == 0) reo[MM] = NNZE;
        }
        base_s[r0] += off0;
        end_s[r0] = off0 + tot0;
        base_s[r1] += off1;
        end_s[r1] = off1 + tot1;
    }
    __syncthreads();

    // bin my quarter (int4-coalesced); flag = global last position of the row
    const int4* rows4 = (const int4*)(d_rows + ((size_t)g << 15) + (b << 13));
    const int4* cols4 = (const int4*)(d_cols + ((size_t)g << 15) + (b << 13));
    const f4v* vals4 = (const f4v*)(d_vals + ((size_t)g << 15) + (b << 13));
    int2* epg = epack + ((size_t)g << 15);
#pragma unroll
    for (int it = 0; it < 2; it++) {
        int4 r = rows4[it * 1024 + t];
        int4 c = cols4[it * 1024 + t];
        f4v v = vals4[it * 1024 + t];
        {
            int sl = atomicAdd(&fill_s[r.x], 1);
            int pos = base_s[r.x] + sl;
            int flag = (pos == end_s[r.x] - 1) ? (int)0x80000000 : 0;
            epg[pos] = make_int2(c.x | flag, __float_as_int(v.x));
        }
        {
            int sl = atomicAdd(&fill_s[r.y], 1);
            int pos = base_s[r.y] + sl;
            int flag = (pos == end_s[r.y] - 1) ? (int)0x80000000 : 0;
            epg[pos] = make_int2(c.y | flag, __float_as_int(v.y));
        }
        {
            int sl = atomicAdd(&fill_s[r.z], 1);
            int pos = base_s[r.z] + sl;
            int flag = (pos == end_s[r.z] - 1) ? (int)0x80000000 : 0;
            epg[pos] = make_int2(c.z | flag, __float_as_int(v.z));
        }
        {
            int sl = atomicAdd(&fill_s[r.w], 1);
            int pos = base_s[r.w] + sl;
            int flag = (pos == end_s[r.w] - 1) ? (int)0x80000000 : 0;
            epg[pos] = make_int2(c.w | flag, __float_as_int(v.w));
        }
    }
}

// ---------------- fused SpMM + mean/max/sum pooling, one wave64 per cluster, fp16 x ----------------
// R0 inner loop (60.6us; best of 4 structures tried -- R11/R12/R14 all regressed: per-CU
// scattered-line rate ~4.4cy/line is the HW ceiling and R0 already sits on it).
// Epilogue writes xdec as split-bf16 (hi + lo = fp32-accurate pair) for the MFMA qkv.
__global__ __launch_bounds__(64) void spmm_pool_kernel(const uint* __restrict__ xh,
                                                       const int* __restrict__ cnt_clu,
                                                       const int* __restrict__ off_clu,
                                                       const int* __restrict__ row_edge_off,
                                                       const int2* __restrict__ epack,
                                                       u16* __restrict__ xdh,
                                                       u16* __restrict__ xdl) {
    // XCD-aware swizzle: bid&7 -> XCD, graphs [8q, 8q+7] on XCD q
    int bid = blockIdx.x;
    int l = bid >> 3;
    int g = ((bid & 7) << 3) + (l >> 6);
    int c = l & 63;
    int h = threadIdx.x;  // 0..63
    int gc = (g << 6) + c;
    int rcnt = cnt_clu[gc];
    int j0 = off_clu[gc];
    const int* reo = row_edge_off + g * (MM + 1) + j0;
    int ebase = reo[0];
    int etot = reo[rcnt] - ebase;
    const long long* ep = (const long long*)(epack + ((size_t)g << 15)) + ebase;
    const uint* xg = xh + ((size_t)g << 17);  // g*N*(H/2) uints
    float2 coef = make_float2(0.f, 0.f), sum = make_float2(0.f, 0.f);
    float2 mx = make_float2(-__builtin_inff(), -__builtin_inff());
    int e = 0;
    for (; e + 16 <= etot; e += 16) {
        long long q[16];
#pragma unroll
        for (int k = 0; k < 16; k++) q[k] = __builtin_nontemporal_load(&ep[e + k]);
        uint xv[16];
#pragma unroll
        for (int k = 0; k < 16; k++)
            xv[k] = xg[(((uint)(int)q[k] & 0x7FFFFFFFu) << 6) + h];
#pragma unroll
        for (int k = 0; k < 16; k++) {
            float v = __int_as_float((int)(q[k] >> 32));
            float2 f = __half22float2(*(__half2*)&xv[k]);
            coef.x = fmaf(v, f.x, coef.x);
            coef.y = fmaf(v, f.y, coef.y);
            if ((int)q[k] < 0) {  // wave-uniform (all lanes see same edge)
                sum.x += coef.x; sum.y += coef.y;
                mx.x = fmaxf(mx.x, coef.x); mx.y = fmaxf(mx.y, coef.y);
                coef.x = 0.f; coef.y = 0.f;
            }
        }
    }
    for (; e < etot; e++) {
        long long q = ep[e];
        uint xv = xg[(((uint)(int)q & 0x7FFFFFFFu) << 6) + h];
        float v = __int_as_float((int)(q >> 32));
        float2 f = __half22float2(*(__half2*)&xv);
        coef.x = fmaf(v, f.x, coef.x);
        coef.y = fmaf(v, f.y, coef.y);
        if ((int)q < 0) {
            sum.x += coef.x; sum.y += coef.y;
            mx.x = fmaxf(mx.x, coef.x); mx.y = fmaxf(mx.y, coef.y);
            coef.x = 0.f; coef.y = 0.f;
        }
    }
    // rows with zero edges contribute coef==0 to the max
    int az = 0;
    for (int j = h; j < rcnt; j += 64) az |= (reo[j + 1] == reo[j]);
    if (__ballot(az) != 0ULL) {
        mx.x = fmaxf(mx.x, 0.f);
        mx.y = fmaxf(mx.y, 0.f);
    }
    float inv = 1.f / (float)(rcnt > 0 ? rcnt : 1);
    // split-bf16 epilogue: lane h owns feature pair (2h, 2h+1) of each of mean|max|sum
    uint* oh = (uint*)xdh + (size_t)gc * 192 + h;
    uint* ol = (uint*)xdl + (size_t)gc * 192 + h;
    float me0 = sum.x * inv, me1 = sum.y * inv;
    u16 a0 = bf16rne(me0), a1 = bf16rne(me1);
    oh[0] = (uint)a0 | ((uint)a1 << 16);
    ol[0] = (uint)bf16rne(me0 - bf16tof(a0)) | ((uint)bf16rne(me1 - bf16tof(a1)) << 16);
    u16 b0 = bf16rne(mx.x), b1 = bf16rne(mx.y);
    oh[64] = (uint)b0 | ((uint)b1 << 16);
    ol[64] = (uint)bf16rne(mx.x - bf16tof(b0)) | ((uint)bf16rne(mx.y - bf16tof(b1)) << 16);
    u16 c0 = bf16rne(sum.x), c1 = bf16rne(sum.y);
    oh[128] = (uint)c0 | ((uint)c1 << 16);
    ol[128] = (uint)bf16rne(sum.x - bf16tof(c0)) | ((uint)bf16rne(sum.y - bf16tof(c1)) << 16);
}

// ---------------- QKV projection via split-bf16 triple-MFMA (verified R15, absmax unchanged) ----------------
__global__ __launch_bounds__(256) void qkv_kernel(const u16* __restrict__ xdh,
                                                  const u16* __restrict__ xdl,
                                                  const u16* __restrict__ WhT,
                                                  const u16* __restrict__ WlT,
                                                  float* __restrict__ QKV) {
    __shared__ u16 Ah[64][40], Al[64][40], Bh[64][40], Bl[64][40];
    int bx = blockIdx.x, by = blockIdx.y;
    int t = threadIdx.x;
    int w = by >> 1;
    int cb = (by & 1) << 6;     // col base within this W
    int r0 = bx << 6;
    const u16* wh = WhT + w * 49152;
    const u16* wl = WlT + w * 49152;
    int lane = t & 63, wv = t >> 6;
    int wm = wv >> 1, wn = wv & 1;          // wave -> 32x32 quadrant
    int srow = t >> 2, sks = (t & 3) << 3;  // staging: row, k-chunk (8 elems)
    int fr = lane & 15, fk = (lane >> 4) << 3;  // fragment row/col + k base
    f32x4 acc[2][2];
#pragma unroll
    for (int i = 0; i < 2; i++)
#pragma unroll
        for (int j = 0; j < 2; j++)
#pragma unroll
            for (int r = 0; r < 4; r++) acc[i][j][r] = 0.f;
    for (int ks = 0; ks < 12; ks++) {
        int k0 = ks << 5;
        bf16x8 sa_h = *(const bf16x8*)&xdh[(size_t)(r0 + srow) * 384 + k0 + sks];
        bf16x8 sa_l = *(const bf16x8*)&xdl[(size_t)(r0 + srow) * 384 + k0 + sks];
        bf16x8 sb_h = *(const bf16x8*)&wh[(size_t)(cb + srow) * 384 + k0 + sks];
        bf16x8 sb_l = *(const bf16x8*)&wl[(size_t)(cb + srow) * 384 + k0 + sks];
        if (ks) __syncthreads();  // previous iteration's fragment reads must finish
        *(bf16x8*)&Ah[srow][sks] = sa_h;
        *(bf16x8*)&Al[srow][sks] = sa_l;
        *(bf16x8*)&Bh[srow][sks] = sb_h;
        *(bf16x8*)&Bl[srow][sks] = sb_l;
        __syncthreads();
        bf16x8 fa_h[2], fa_l[2], fb_h[2], fb_l[2];
#pragma unroll
        for (int mi = 0; mi < 2; mi++) {
            int ar = (wm << 5) + (mi << 4) + fr;
            fa_h[mi] = *(const bf16x8*)&Ah[ar][fk];
            fa_l[mi] = *(const bf16x8*)&Al[ar][fk];
        }
#pragma unroll
        for (int ni = 0; ni < 2; ni++) {
            int br = (wn << 5) + (ni << 4) + fr;
            fb_h[ni] = *(const bf16x8*)&Bh[br][fk];
            fb_l[ni] = *(const bf16x8*)&Bl[br][fk];
        }
#pragma unroll
        for (int mi = 0; mi < 2; mi++)
#pragma unroll
            for (int ni = 0; ni < 2; ni++) {
                acc[mi][ni] = __builtin_amdgcn_mfma_f32_16x16x32_bf16(
                    fa_h[mi], fb_h[ni], acc[mi][ni], 0, 0, 0);
                acc[mi][ni] = __builtin_amdgcn_mfma_f32_16x16x32_bf16(
                    fa_h[mi], fb_l[ni], acc[mi][ni], 0, 0, 0);
                acc[mi][ni] = __builtin_amdgcn_mfma_f32_16x16x32_bf16(
                    fa_l[mi], fb_h[ni], acc[mi][ni], 0, 0, 0);
            }
    }
#pragma unroll
    for (int mi = 0; mi < 2; mi++)
#pragma unroll
        for (int ni = 0; ni < 2; ni++)
#pragma unroll
            for (int r = 0; r < 4; r++) {
                int row = r0 + (wm << 5) + (mi << 4) + ((lane >> 4) << 2) + r;
                int col = (by << 6) + (wn << 5) + (ni << 4) + (lane & 15);
                QKV[(size_t)row * TH + col] = acc[mi][ni][r];
            }
}

// ---------------- per-graph 64x64 attention ----------------
__global__ __launch_bounds__(256) void attn_kernel(const float* __restrict__ QKV,
                                                   float* __restrict__ out) {
    __shared__ float Qs[16][132];
    __shared__ float sc[16][68];
    int g = blockIdx.x;
    int q0 = blockIdx.y * 16;
    int t = threadIdx.x;
    const float* base = QKV + (size_t)(g * CC) * TH;
    for (int u = t; u < 512; u += 256) {
        int i = u >> 5, cc = u & 31;
        *(float4*)&Qs[i][cc * 4] = *(const float4*)&base[(size_t)(q0 + i) * TH + cc * 4];
    }
    __syncthreads();
    {  // scores: thread (iq, j) computes rows iq, iq+4, iq+8, iq+12 vs col j
        int j = t & 63, iq = t >> 6;
        float a0 = 0, a1 = 0, a2 = 0, a3 = 0;
        const float* Krow = base + (size_t)j * TH + HH;
#pragma unroll 4
        for (int cc = 0; cc < 32; cc++) {
            float4 kv = *(const float4*)&Krow[cc * 4];
            float4 q0v = *(float4*)&Qs[iq][cc * 4];
            float4 q1v = *(float4*)&Qs[4 + iq][cc * 4];
            float4 q2v = *(float4*)&Qs[8 + iq][cc * 4];
            float4 q3v = *(float4*)&Qs[12 + iq][cc * 4];
            a0 += kv.x * q0v.x + kv.y * q0v.y + kv.z * q0v.z + kv.w * q0v.w;
            a1 += kv.x * q1v.x + kv.y * q1v.y + kv.z * q1v.z + kv.w * q1v.w;
            a2 += kv.x * q2v.x + kv.y * q2v.y + kv.z * q2v.z + kv.w * q2v.w;
            a3 += kv.x * q3v.x + kv.y * q3v.y + kv.z * q3v.z + kv.w * q3v.w;
        }
        const float scale = 0.08838834764831845f;  // 1/sqrt(128)
        sc[iq][j] = a0 * scale;
        sc[4 + iq][j] = a1 * scale;
        sc[8 + iq][j] = a2 * scale;
        sc[12 + iq][j] = a3 * scale;
    }
    __syncthreads();
    {  // softmax: 16 threads per row, 4 cols each
        int i = t >> 4, l = t & 15;
        float4 sv = *(float4*)&sc[i][l * 4];
        float m = fmaxf(fmaxf(sv.x, sv.y), fmaxf(sv.z, sv.w));
#pragma unroll
        for (int d = 1; d < 16; d <<= 1) m = fmaxf(m, __shfl_xor(m, d));
        float4 p;
        p.x = __expf(sv.x - m);
        p.y = __expf(sv.y - m);
        p.z = __expf(sv.z - m);
        p.w = __expf(sv.w - m);
        float s = p.x + p.y + p.z + p.w;
#pragma unroll
        for (int d = 1; d < 16; d <<= 1) s += __shfl_xor(s, d);
        float inv = 1.0f / s;
        p.x *= inv; p.y *= inv; p.z *= inv; p.w *= inv;
        *(float4*)&sc[i][l * 4] = p;
    }
    __syncthreads();
    {  // PV: thread (i, hq) computes out[i][hq*8 .. +8)
        int i = t >> 4, hq = t & 15;
        const float* Vbase = base + 2 * HH;
        float acc[8] = {};
        for (int j = 0; j < 64; j++) {
            float d = sc[i][j];
            float4 v0 = *(const float4*)&Vbase[(size_t)j * TH + hq * 8];
            float4 v1 = *(const float4*)&Vbase[(size_t)j * TH + hq * 8 + 4];
            acc[0] = fmaf(d, v0.x, acc[0]);
            acc[1] = fmaf(d, v0.y, acc[1]);
            acc[2] = fmaf(d, v0.z, acc[2]);
            acc[3] = fmaf(d, v0.w, acc[3]);
            acc[4] = fmaf(d, v1.x, acc[4]);
            acc[5] = fmaf(d, v1.y, acc[5]);
            acc[6] = fmaf(d, v1.z, acc[6]);
            acc[7] = fmaf(d, v1.w, acc[7]);
        }
        float* op = out + (size_t)g * (CC * HH) + (size_t)(q0 + i) * HH + hq * 8;
        *(float4*)&op[0] = make_float4(acc[0], acc[1], acc[2], acc[3]);
        *(float4*)&op[4] = make_float4(acc[4], acc[5], acc[6], acc[7]);
    }
}

extern "C" void kernel_launch(void* const* d_in, const int* in_sizes, int n_in,
                              void* d_out, int out_size, void* d_ws, size_t ws_size,
                              hipStream_t stream) {
    const float* x = (const float*)d_in[0];
    // d_in[1] = batch (unused: nodes sorted, equal graph sizes), d_in[2] = batch_size (compile-time 64)
    const int* d_rows = (const int*)d_in[3];
    const int* d_cols = (const int*)d_in[4];
    const float* d_vals = (const float*)d_in[5];
    const int* d_index = (const int*)d_in[6];
    const float* Wq = (const float*)d_in[7];
    const float* Wk = (const float*)d_in[8];
    const float* Wv = (const float*)d_in[9];
    float* out = (float*)d_out;

    char* ws = (char*)d_ws;
    size_t o = 0;
    uint* xh = (uint*)(ws + o); o += (size_t)BG * NN * (HH / 2) * 4;  // 32 MB fp16 x
    int2* epack = (int2*)(ws + o); o += (size_t)BG * NNZE * 8;        // 16 MB
    int* cnt_blk = (int*)(ws + o); o += (size_t)BG * 4 * MM * 4;      // 2 MB
    int* row_edge_off = (int*)(ws + o); o += (size_t)BG * (MM + 1) * 4;
    int* cnt_clu = (int*)(ws + o); o += (size_t)BG * CC * 4;
    int* off_clu = (int*)(ws + o); o += (size_t)BG * CC * 4;
    u16* xdh = (u16*)(ws + o); o += (size_t)BG * CC * TH * 2;   // 3 MB split-bf16 hi
    u16* xdl = (u16*)(ws + o); o += (size_t)BG * CC * TH * 2;   // 3 MB split-bf16 lo
    u16* WhT = (u16*)(ws + o); o += (size_t)3 * HH * TH * 2;    // 288 KB W^T hi
    u16* WlT = (u16*)(ws + o); o += (size_t)3 * HH * TH * 2;    // 288 KB W^T lo
    float* QKV = (float*)(ws + o); o += (size_t)BG * CC * TH * 4;

    prep_count_kernel<<<BG * 4, 1024, 0, stream>>>(d_rows, x, Wq, Wk, Wv,
                                                   cnt_blk, xh, WhT, WlT);
    prep_scanbin_kernel<<<BG * 4, 1024, 0, stream>>>(d_rows, d_cols, d_vals, d_index,
                                                     cnt_blk,
                                                     cnt_clu, off_clu, row_edge_off, epack);
    spmm_pool_kernel<<<BG * CC, 64, 0, stream>>>(xh, cnt_clu, off_clu, row_edge_off,
                                                 epack, xdh, xdl);
    qkv_kernel<<<dim3(64, 6), 256, 0, stream>>>(xdh, xdl, WhT, WlT, QKV);
    attn_kernel<<<dim3(BG, 4), 256, 0, stream>>>(QKV, out);
}